// Round 1
// baseline (8017.867 us; speedup 1.0000x reference)
//
#include <hip/hip_runtime.h>

#define BB   8
#define TT   16
#define NPIX 784
#define WIDE 28

__device__ __forceinline__ float sigm_(float x) { return 1.0f / (1.0f + __expf(-x)); }
__device__ __forceinline__ float tanh_(float x) { return 2.0f / (1.0f + __expf(-2.0f * x)) - 1.0f; }

// One block = (hc, b). Computes all 4 gates for channel hc across 784 pixels,
// then the LSTM pointwise update. Weights for this hc staged in LDS as
// [cin][ky][kx][gate] so one float4 read gives all 4 gate weights per tap.
template<int CX, int HC, bool WRITE_OUT, bool USE_PRE>
__global__ __launch_bounds__(256)
void cell_kernel(const float* __restrict__ xin, long xbstride,
                 const float* __restrict__ gpre, long gbstride,
                 const float* __restrict__ hin,
                 float* __restrict__ hout,
                 float* __restrict__ cbuf,
                 const float* __restrict__ Wx,
                 const float* __restrict__ bxp,
                 const float* __restrict__ Wh,
                 const float* __restrict__ Wp,
                 float* __restrict__ out2, long obstride)
{
    constexpr int CINT = CX + HC;
    __shared__ __align__(16) float wlds[CINT * 36];
    const int hc  = blockIdx.x;
    const int b   = blockIdx.y;
    const int tid = threadIdx.x;

    for (int idx = tid; idx < CINT * 36; idx += 256) {
        int cin = idx / 36;
        int r   = idx - cin * 36;
        int ky  = r / 12;
        int r2  = r - ky * 12;
        int kx  = r2 >> 2;
        int g   = r2 & 3;
        int ch  = g * HC + hc;
        float w;
        if (cin < CX) w = Wx[((long)ch * CX + cin) * 9 + ky * 3 + kx];
        else          w = Wh[((long)ch * HC + (cin - CX)) * 9 + ky * 3 + kx];
        wlds[idx] = w;
    }
    __syncthreads();

    int py[4], px[4];
    bool pv[4];
#pragma unroll
    for (int j = 0; j < 4; ++j) {
        int p = tid + j * 256;
        pv[j] = (p < NPIX);
        int y = p / WIDE;
        px[j] = p - y * WIDE;
        py[j] = pv[j] ? y : -1000;   // kills all taps for invalid slots
    }

    float acc[4][4];
#pragma unroll
    for (int g = 0; g < 4; ++g)
#pragma unroll
        for (int j = 0; j < 4; ++j) acc[g][j] = 0.0f;

    if (USE_PRE) {
        const float* gb = gpre + (long)b * gbstride;
#pragma unroll
        for (int g = 0; g < 4; ++g) {
            const float* gp = gb + (long)(g * HC + hc) * NPIX;
#pragma unroll
            for (int j = 0; j < 4; ++j) {
                int p = tid + j * 256;
                if (pv[j]) acc[g][j] = gp[p];
            }
        }
    }

    const float* xplane = (CX > 0) ? (xin + (long)b * xbstride) : nullptr;
    const float* hplane = hin + (long)b * HC * NPIX;

    for (int cin = 0; cin < CINT; ++cin) {
        const float* plane = (cin < CX) ? (xplane + (long)cin * NPIX)
                                        : (hplane + (long)(cin - CX) * NPIX);
        const float* wrow = &wlds[cin * 36];
#pragma unroll
        for (int ky = 0; ky < 3; ++ky) {
#pragma unroll
            for (int kx = 0; kx < 3; ++kx) {
                float4 w = *(const float4*)(wrow + (ky * 3 + kx) * 4);
#pragma unroll
                for (int j = 0; j < 4; ++j) {
                    int rr = py[j] + ky - 1;
                    int cc = px[j] + kx - 1;
                    float v = 0.0f;
                    if (rr >= 0 && rr < WIDE && cc >= 0 && cc < WIDE)
                        v = plane[rr * WIDE + cc];
                    acc[0][j] = fmaf(v, w.x, acc[0][j]);
                    acc[1][j] = fmaf(v, w.y, acc[1][j]);
                    acc[2][j] = fmaf(v, w.z, acc[2][j]);
                    acc[3][j] = fmaf(v, w.w, acc[3][j]);
                }
            }
        }
    }

    const float bi = bxp[0 * HC + hc];
    const float bf = bxp[1 * HC + hc];
    const float bg = bxp[2 * HC + hc];
    const float bo = bxp[3 * HC + hc];
    float* crow = cbuf + ((long)b * HC + hc) * NPIX;
    float* hrow = hout + ((long)b * HC + hc) * NPIX;
    const float* pip = Wp + (long)(0 * HC + hc) * NPIX;
    const float* pfp = Wp + (long)(1 * HC + hc) * NPIX;
    const float* pop = Wp + (long)(2 * HC + hc) * NPIX;

#pragma unroll
    for (int j = 0; j < 4; ++j) {
        if (!pv[j]) continue;
        int p = tid + j * 256;
        float cprev = crow[p];
        float ig = sigm_(acc[0][j] + bi + cprev * pip[p]);
        float fg = sigm_(acc[1][j] + bf + cprev * pfp[p]);
        float gg = tanh_(acc[2][j] + bg);
        float cn = fg * cprev + ig * gg;
        float og = sigm_(acc[3][j] + bo + cn * pop[p]);
        float hn = og * tanh_(cn);
        crow[p] = cn;
        hrow[p] = hn;
        if (WRITE_OUT) out2[(long)b * obstride + (long)hc * NPIX + p] = hn;
    }
}

// Time-parallel precompute of gx0 = conv(x, Wx0) (no bias) over all B*T images.
template<int CX, int HC>
__global__ __launch_bounds__(256)
void conv_pre_kernel(const float* __restrict__ x,   // (B*T, CX, 784)
                     const float* __restrict__ Wx,  // (4HC, CX, 3, 3)
                     float* __restrict__ gout)      // (B*T, 4HC, 784)
{
    __shared__ __align__(16) float wlds[CX * 36];
    const int hc  = blockIdx.x;
    const int bt  = blockIdx.y;
    const int tid = threadIdx.x;

    for (int idx = tid; idx < CX * 36; idx += 256) {
        int cin = idx / 36;
        int r   = idx - cin * 36;
        int ky  = r / 12;
        int r2  = r - ky * 12;
        int kx  = r2 >> 2;
        int g   = r2 & 3;
        wlds[idx] = Wx[((long)(g * HC + hc) * CX + cin) * 9 + ky * 3 + kx];
    }
    __syncthreads();

    int py[4], px[4];
    bool pv[4];
#pragma unroll
    for (int j = 0; j < 4; ++j) {
        int p = tid + j * 256;
        pv[j] = (p < NPIX);
        int y = p / WIDE;
        px[j] = p - y * WIDE;
        py[j] = pv[j] ? y : -1000;
    }

    float acc[4][4];
#pragma unroll
    for (int g = 0; g < 4; ++g)
#pragma unroll
        for (int j = 0; j < 4; ++j) acc[g][j] = 0.0f;

    const float* xb = x + (long)bt * CX * NPIX;
    for (int cin = 0; cin < CX; ++cin) {
        const float* plane = xb + (long)cin * NPIX;
        const float* wrow = &wlds[cin * 36];
#pragma unroll
        for (int ky = 0; ky < 3; ++ky) {
#pragma unroll
            for (int kx = 0; kx < 3; ++kx) {
                float4 w = *(const float4*)(wrow + (ky * 3 + kx) * 4);
#pragma unroll
                for (int j = 0; j < 4; ++j) {
                    int rr = py[j] + ky - 1;
                    int cc = px[j] + kx - 1;
                    float v = 0.0f;
                    if (rr >= 0 && rr < WIDE && cc >= 0 && cc < WIDE)
                        v = plane[rr * WIDE + cc];
                    acc[0][j] = fmaf(v, w.x, acc[0][j]);
                    acc[1][j] = fmaf(v, w.y, acc[1][j]);
                    acc[2][j] = fmaf(v, w.z, acc[2][j]);
                    acc[3][j] = fmaf(v, w.w, acc[3][j]);
                }
            }
        }
    }

#pragma unroll
    for (int g = 0; g < 4; ++g) {
        float* gp = gout + ((long)bt * 4 * HC + (long)g * HC + hc) * NPIX;
#pragma unroll
        for (int j = 0; j < 4; ++j) {
            int p = tid + j * 256;
            if (pv[j]) gp[p] = acc[g][j];
        }
    }
}

extern "C" void kernel_launch(void* const* d_in, const int* in_sizes, int n_in,
                              void* d_out, int out_size, void* d_ws, size_t ws_size,
                              hipStream_t stream)
{
    const float* x   = (const float*)d_in[0];
    const float* Wx0 = (const float*)d_in[1];
    const float* bx0 = (const float*)d_in[2];
    const float* Wh0 = (const float*)d_in[3];
    const float* Wp0 = (const float*)d_in[4];
    const float* Wx1 = (const float*)d_in[5];
    const float* bx1 = (const float*)d_in[6];
    const float* Wh1 = (const float*)d_in[7];
    const float* Wp1 = (const float*)d_in[8];
    const float* Wx2 = (const float*)d_in[9];
    const float* bx2 = (const float*)d_in[10];
    const float* Wh2 = (const float*)d_in[11];
    const float* Wp2 = (const float*)d_in[12];
    (void)in_sizes; (void)n_in; (void)out_size;

    float* out = (float*)d_out;
    float* ws  = (float*)d_ws;

    const long S64 = (long)BB * 64 * NPIX;   // 401408
    const long S32 = (long)BB * 32 * NPIX;   // 200704

    float* h0a = ws;        float* h0b = h0a + S64; float* c0 = h0b + S64;
    float* h1a = c0 + S64;  float* h1b = h1a + S32; float* c1 = h1b + S32;
    float* h2a = c1 + S32;  float* h2b = h2a + S64; float* c2 = h2b + S64;
    float* state_end = c2 + S64;
    const long state_floats = (long)(state_end - ws);           // 3,010,560
    float* gx0 = state_end;
    const long gx0_floats = (long)BB * TT * 256 * NPIX;         // 25,690,112
    const bool use_pre =
        (long)ws_size >= (state_floats + gx0_floats) * (long)sizeof(float);

    // zero-init h/c state (ws is re-poisoned before every timed call)
    hipMemsetAsync(d_ws, 0, (size_t)state_floats * sizeof(float), stream);

    if (use_pre) {
        // x is (B,T,C,H,W) contiguous -> (B*T, 192, 784)
        conv_pre_kernel<192, 64><<<dim3(64, BB * TT), 256, 0, stream>>>(x, Wx0, gx0);
    }

    float* h0[2] = { h0a, h0b };
    float* h1[2] = { h1a, h1b };
    float* h2[2] = { h2a, h2b };

    for (int t = 0; t < TT; ++t) {
        const int cur = t & 1, nxt = cur ^ 1;
        if (use_pre) {
            cell_kernel<0, 64, false, true><<<dim3(64, BB), 256, 0, stream>>>(
                nullptr, 0,
                gx0 + (long)t * 256 * NPIX, (long)TT * 256 * NPIX,
                h0[cur], h0[nxt], c0, Wx0, bx0, Wh0, Wp0, nullptr, 0);
        } else {
            cell_kernel<192, 64, false, false><<<dim3(64, BB), 256, 0, stream>>>(
                x + (long)t * 192 * NPIX, (long)TT * 192 * NPIX,
                nullptr, 0,
                h0[cur], h0[nxt], c0, Wx0, bx0, Wh0, Wp0, nullptr, 0);
        }
        cell_kernel<64, 32, false, false><<<dim3(32, BB), 256, 0, stream>>>(
            h0[nxt], (long)64 * NPIX, nullptr, 0,
            h1[cur], h1[nxt], c1, Wx1, bx1, Wh1, Wp1, nullptr, 0);
        cell_kernel<32, 64, true, false><<<dim3(64, BB), 256, 0, stream>>>(
            h1[nxt], (long)32 * NPIX, nullptr, 0,
            h2[cur], h2[nxt], c2, Wx2, bx2, Wh2, Wp2,
            out + (long)t * 64 * NPIX, (long)TT * 64 * NPIX);
    }
}